// Round 3
// baseline (245.622 us; speedup 1.0000x reference)
//
#include <hip/hip_runtime.h>
#include <hip/hip_bf16.h>
#include <cstdint>
#include <cstddef>

// Sizes fixed by the reference problem.
#define DMODEL 1024
#define BATCH  4
#define SEQ    4096
#define BSROWS (BATCH*SEQ)     // 16384
#define CHUNK  32
#define NCHUNK (SEQ/CHUNK)     // 128
#define NCH_T  (BATCH*NCHUNK)  // 512 total chunks

typedef __attribute__((ext_vector_type(8))) short bf16x8;
typedef __attribute__((ext_vector_type(4))) float f32x4;

// ---- helpers ---------------------------------------------------------------

__device__ __forceinline__ unsigned short f2bf(float f) {
  union { float f; uint32_t u; } v; v.f = f;
  uint32_t u = v.u;
  u += 0x7FFFu + ((u >> 16) & 1u);   // round-to-nearest-even
  return (unsigned short)(u >> 16);
}

__device__ __forceinline__ float sigmoid_dev(const float* dp) {
  return 1.0f / (1.0f + expf(-dp[0]));
}

typedef __attribute__((address_space(1))) void void_g;
typedef __attribute__((address_space(3))) void void_l;

__device__ __forceinline__ void gl2lds16(const void* g, void* l) {
  __builtin_amdgcn_global_load_lds((void_g*)g, (void_l*)l, 16, 0, 0);
}

// ---- shared 64x64-tile NT K-loop (BK=64, XOR-swizzled LDS) -----------------
// Layout: LDS row = 64 bf16 = 8 chunks of 16B. Chunk slot q holds global
// chunk q ^ (row&7); staging swizzles the GLOBAL address per lane so the LDS
// destination stays wave-uniform-base + lane*16 (global_load_lds constraint).
__device__ __forceinline__ void kloop64(
    const unsigned short* __restrict__ A, const unsigned short* __restrict__ B,
    int m0, int n0, f32x4 acc[2][2],
    unsigned short* As, unsigned short* Bs, int tid) {
  int lane = tid & 63, w = tid >> 6, wm = w & 1, wn = w >> 1;
  int quad = lane >> 4, l16 = lane & 15;
  int r = tid >> 3, cch = tid & 7;
  int g = cch ^ (r & 7);
  const bf16x8* Av = (const bf16x8*)As;
  const bf16x8* Bv = (const bf16x8*)Bs;
  for (int k0 = 0; k0 < DMODEL; k0 += 64) {
    gl2lds16(A + (size_t)(m0 + r) * DMODEL + k0 + g * 8,      As + r * 64 + cch * 8);
    gl2lds16(A + (size_t)(m0 + 32 + r) * DMODEL + k0 + g * 8, As + (32 + r) * 64 + cch * 8);
    gl2lds16(B + (size_t)(n0 + r) * DMODEL + k0 + g * 8,      Bs + r * 64 + cch * 8);
    gl2lds16(B + (size_t)(n0 + 32 + r) * DMODEL + k0 + g * 8, Bs + (32 + r) * 64 + cch * 8);
    __syncthreads();
    #pragma unroll
    for (int kk = 0; kk < 2; ++kk) {
      bf16x8 af[2], bfr[2];
      #pragma unroll
      for (int i = 0; i < 2; ++i) {
        int rowA = wm * 32 + i * 16 + l16;
        af[i]  = Av[rowA * 8 + ((kk * 4 + quad) ^ (l16 & 7))];
        int rowB = wn * 32 + i * 16 + l16;
        bfr[i] = Bv[rowB * 8 + ((kk * 4 + quad) ^ (l16 & 7))];
      }
      #pragma unroll
      for (int i = 0; i < 2; ++i)
        #pragma unroll
        for (int j = 0; j < 2; ++j)
          acc[i][j] = __builtin_amdgcn_mfma_f32_16x16x32_bf16(af[i], bfr[j], acc[i][j], 0, 0, 0);
    }
    __syncthreads();
  }
}

// ---- fused prep ------------------------------------------------------------
// blocks [0,512)    : single-pass local scan: hv = l_s (bf16), carry, lbeta
// blocks [512,1536) : W_f f32 -> bf16
// blocks [1536,2560): W_up f32 [c][d] -> bf16 transposed [d][c]
// blocks [2560,2816): bb[e] = dot(W_f[e,:], b_up)
__global__ __launch_bounds__(256) void prep_kernel(
    const float* __restrict__ x, const float* __restrict__ mask,
    const float* __restrict__ W_up, const float* __restrict__ b_up,
    const float* __restrict__ W_f, const float* __restrict__ dp,
    unsigned short* __restrict__ Wf_bf, unsigned short* __restrict__ WupT,
    float* __restrict__ bb, unsigned short* __restrict__ hv,
    float* __restrict__ carry, float* __restrict__ lbeta,
    float* __restrict__ cbeta) {
  __shared__ float tile[32][33];
  int blk = blockIdx.x;
  int tid = threadIdx.x;

  if (blk < 512) {
    float decay = sigmoid_dev(dp);
    int b = blk / NCHUNK, c = blk % NCHUNK;
    int base = b * SEQ + c * CHUNK;
    const float4* xp = (const float4*)(x + (size_t)base * DMODEL);
    const float* mp = mask + base;
    float4 h = make_float4(0.f, 0.f, 0.f, 0.f);
    float hb = 0.f;
    #pragma unroll 8
    for (int s = 0; s < CHUNK; ++s) {
      float m = mp[s];
      float4 xv = xp[(size_t)s * (DMODEL / 4) + tid];
      h.x = decay * h.x + m * xv.x;
      h.y = decay * h.y + m * xv.y;
      h.z = decay * h.z + m * xv.z;
      h.w = decay * h.w + m * xv.w;
      hb = decay * hb + m;
      ushort4 o;
      o.x = f2bf(h.x); o.y = f2bf(h.y); o.z = f2bf(h.z); o.w = f2bf(h.w);
      ((ushort4*)hv)[(size_t)(base + s) * (DMODEL / 4) + tid] = o;
      if (tid == 0) lbeta[base + s] = hb;
    }
    ((float4*)carry)[(size_t)blk * (DMODEL / 4) + tid] = h;
    if (tid == 0) cbeta[blk] = hb;
  } else if (blk < 1536) {
    int i = (blk - 512) * 256 + tid;     // over D*D/4 float4s
    float4 v = ((const float4*)W_f)[i];
    ushort4 o;
    o.x = f2bf(v.x); o.y = f2bf(v.y); o.z = f2bf(v.z); o.w = f2bf(v.w);
    ((ushort4*)Wf_bf)[i] = o;
  } else if (blk < 2560) {
    int id = blk - 1536;
    int bx = id & 31, by = id >> 5;
    int tx = tid & 31, ty = tid >> 5;   // 32 x 8
    int xx = bx * 32 + tx;
    int y0 = by * 32;
    for (int j = ty; j < 32; j += 8)
      tile[j][tx] = W_up[(size_t)(y0 + j) * DMODEL + xx];
    __syncthreads();
    int ox = by * 32 + tx;
    int oy0 = bx * 32;
    for (int j = ty; j < 32; j += 8)
      WupT[(size_t)(oy0 + j) * DMODEL + ox] = f2bf(tile[tx][j]);
  } else {
    int w = tid >> 6;
    int lane = tid & 63;
    int e = (blk - 2560) * 4 + w;
    float s = 0.f;
    for (int i = lane; i < DMODEL; i += 64)
      s += W_f[(size_t)e * DMODEL + i] * b_up[i];
    #pragma unroll
    for (int off = 32; off; off >>= 1) s += __shfl_down(s, off);
    if (lane == 0) bb[e] = s;
  }
}

// ---- mid2: gemm_wc (256 blocks, 64x64) + chunk-level scan (16 blocks) ------
__global__ __launch_bounds__(256) void mid2_kernel(
    const unsigned short* __restrict__ Wf_bf,
    const unsigned short* __restrict__ WupT,
    unsigned short* __restrict__ Wc,
    const float* __restrict__ carry, const float* __restrict__ cbeta,
    const float* __restrict__ dp,
    unsigned short* __restrict__ Pbf, float* __restrict__ pbeta) {
  __shared__ unsigned short As[64 * 64];
  __shared__ unsigned short Bs[64 * 64];
  int tid = threadIdx.x;
  if (blockIdx.x < 256) {
    // Wc[e][d] = sum_c Wf[e][c] * WupT[d][c]
    int mt = blockIdx.x >> 4, nt = blockIdx.x & 15;
    f32x4 acc[2][2] = {};
    kloop64(Wf_bf, WupT, mt * 64, nt * 64, acc, As, Bs, tid);
    int lane = tid & 63, w = tid >> 6, wm = w & 1, wn = w >> 1;
    int quad = lane >> 4, l16 = lane & 15;
    #pragma unroll
    for (int j = 0; j < 2; ++j) {
      int col = nt * 64 + wn * 32 + j * 16 + l16;
      #pragma unroll
      for (int i = 0; i < 2; ++i) {
        int rowb = mt * 64 + wm * 32 + i * 16 + quad * 4;
        #pragma unroll
        for (int rr = 0; rr < 4; ++rr)
          Wc[(size_t)(rowb + rr) * DMODEL + col] = f2bf(acc[i][j][rr]);
      }
    }
  } else {
    // exclusive chunk scan: Pbf[c] = state entering chunk c (bf16), pbeta f32
    float decay = sigmoid_dev(dp);
    float dL = powf(decay, (float)CHUNK);
    int gid = (blockIdx.x - 256) * 256 + tid;   // 0 .. 4095
    int b = gid >> 10, dd = gid & 1023;
    float P = 0.f;
    for (int c0 = 0; c0 < NCHUNK; c0 += 8) {
      float v[8];
      #pragma unroll
      for (int j = 0; j < 8; ++j)
        v[j] = carry[(size_t)(b * NCHUNK + c0 + j) * DMODEL + dd];
      #pragma unroll
      for (int j = 0; j < 8; ++j) {
        Pbf[(size_t)(b * NCHUNK + c0 + j) * DMODEL + dd] = f2bf(P);
        P = dL * P + v[j];
      }
    }
    if (dd == 0) {
      float Pb = 0.f;
      for (int c0 = 0; c0 < NCHUNK; c0 += 16) {
        float v[16];
        #pragma unroll
        for (int j = 0; j < 16; ++j) v[j] = cbeta[b * NCHUNK + c0 + j];
        #pragma unroll
        for (int j = 0; j < 16; ++j) {
          pbeta[b * NCHUNK + c0 + j] = Pb;
          Pb = dL * Pb + v[j];
        }
      }
    }
  }
}

// ---- pout: Pout[c][e] = sum_d Pbf[c][d]*Wc[e][d] + pbeta[c]*bb[e] ----------
__global__ __launch_bounds__(256) void pout_kernel(
    const unsigned short* __restrict__ Pbf,
    const unsigned short* __restrict__ Wc,
    const float* __restrict__ pbeta, const float* __restrict__ bb,
    float* __restrict__ Pout) {
  __shared__ unsigned short As[64 * 64];
  __shared__ unsigned short Bs[64 * 64];
  int tid = threadIdx.x;
  int mt = blockIdx.x >> 4, nt = blockIdx.x & 15;  // 8 x 16
  f32x4 acc[2][2] = {};
  kloop64(Pbf, Wc, mt * 64, nt * 64, acc, As, Bs, tid);
  int lane = tid & 63, w = tid >> 6, wm = w & 1, wn = w >> 1;
  int quad = lane >> 4, l16 = lane & 15;
  #pragma unroll
  for (int j = 0; j < 2; ++j) {
    int col = nt * 64 + wn * 32 + j * 16 + l16;
    float bbv = bb[col];
    #pragma unroll
    for (int i = 0; i < 2; ++i) {
      int rowb = mt * 64 + wm * 32 + i * 16 + quad * 4;
      #pragma unroll
      for (int rr = 0; rr < 4; ++rr) {
        int row = rowb + rr;
        Pout[(size_t)row * DMODEL + col] = acc[i][j][rr] + pbeta[row] * bbv;
      }
    }
  }
}

// ---- main GEMM: out = hv@Wc^T + decay^(s+1)*Pout[chunk] + lbeta*bb + b_f ---
// 128x128 tile, BK=64, XOR-swizzled LDS, XCD-friendly m-major block mapping.
__global__ __launch_bounds__(256) void gemm_main(
    const unsigned short* __restrict__ A,    // hv (local scans) bf16 [16384][1024]
    const unsigned short* __restrict__ Bm,   // Wc bf16 [1024][1024] rows=e
    const float* __restrict__ Pout,          // [512][1024]
    const float* __restrict__ lbeta,
    const float* __restrict__ bb,
    const float* __restrict__ bias_f,
    const float* __restrict__ dp,
    float* __restrict__ out) {
  __shared__ unsigned short As[128 * 64];   // 16 KB
  __shared__ unsigned short Bs[128 * 64];   // 16 KB
  __shared__ float dpow[CHUNK];
  int tid = threadIdx.x;
  if (tid < CHUNK) {
    float decay = sigmoid_dev(dp);
    dpow[tid] = powf(decay, (float)(tid + 1));
  }
  int lane = tid & 63, w = tid >> 6, wm = w & 1, wn = w >> 1;
  int quad = lane >> 4, l16 = lane & 15;
  int r = tid >> 3, cch = tid & 7;
  int g = cch ^ (r & 7);
  int m0 = (blockIdx.x & 127) * 128;   // consecutive blk -> same XCD shares A tiles
  int n0 = (blockIdx.x >> 7) * 128;
  f32x4 acc[4][4] = {};
  const bf16x8* Av = (const bf16x8*)As;
  const bf16x8* Bv = (const bf16x8*)Bs;
  for (int k0 = 0; k0 < DMODEL; k0 += 64) {
    #pragma unroll
    for (int q = 0; q < 4; ++q) {
      gl2lds16(A  + (size_t)(m0 + q * 32 + r) * DMODEL + k0 + g * 8,
               As + (q * 32 + r) * 64 + cch * 8);
      gl2lds16(Bm + (size_t)(n0 + q * 32 + r) * DMODEL + k0 + g * 8,
               Bs + (q * 32 + r) * 64 + cch * 8);
    }
    __syncthreads();
    #pragma unroll
    for (int kk = 0; kk < 2; ++kk) {
      bf16x8 af[4], bfr[4];
      #pragma unroll
      for (int i = 0; i < 4; ++i) {
        int rowA = wm * 64 + i * 16 + l16;
        af[i]  = Av[rowA * 8 + ((kk * 4 + quad) ^ (l16 & 7))];
        int rowB = wn * 64 + i * 16 + l16;
        bfr[i] = Bv[rowB * 8 + ((kk * 4 + quad) ^ (l16 & 7))];
      }
      #pragma unroll
      for (int i = 0; i < 4; ++i)
        #pragma unroll
        for (int j = 0; j < 4; ++j)
          acc[i][j] = __builtin_amdgcn_mfma_f32_16x16x32_bf16(af[i], bfr[j], acc[i][j], 0, 0, 0);
    }
    __syncthreads();
  }
  #pragma unroll
  for (int j = 0; j < 4; ++j) {
    int col = n0 + wn * 64 + j * 16 + l16;
    float bbv = bb[col];
    float bfv = bias_f[col];
    #pragma unroll
    for (int i = 0; i < 4; ++i) {
      int rowb = m0 + wm * 64 + i * 16 + quad * 4;
      #pragma unroll
      for (int rr = 0; rr < 4; ++rr) {
        int row = rowb + rr;
        float po = Pout[(size_t)(row >> 5) * DMODEL + col];
        out[(size_t)row * DMODEL + col] =
            acc[i][j][rr] + dpow[row & 31] * po + lbeta[row] * bbv + bfv;
      }
    }
  }
}

// ---- launch ----------------------------------------------------------------

extern "C" void kernel_launch(void* const* d_in, const int* in_sizes, int n_in,
                              void* d_out, int out_size, void* d_ws, size_t ws_size,
                              hipStream_t stream) {
  const float* x    = (const float*)d_in[0];
  const float* mask = (const float*)d_in[1];
  const float* W_up = (const float*)d_in[2];
  const float* b_up = (const float*)d_in[3];
  const float* W_f  = (const float*)d_in[4];
  const float* b_f  = (const float*)d_in[5];
  const float* dp   = (const float*)d_in[6];
  float* out = (float*)d_out;

  char* ws = (char*)d_ws;
  unsigned short* hv    = (unsigned short*)(ws);                 // 32 MB
  unsigned short* Wc    = (unsigned short*)(ws + 33554432);      // 2 MB
  unsigned short* Wf_bf = (unsigned short*)(ws + 35651584);      // 2 MB
  unsigned short* WupT  = (unsigned short*)(ws + 37748736);      // 2 MB
  float* carry  = (float*)(ws + 39845888);                       // 2 MB
  unsigned short* Pbf = (unsigned short*)(ws + 41943040);        // 1 MB
  float* Pout   = (float*)(ws + 42991616);                       // 2 MB
  float* lbeta  = (float*)(ws + 45088768);                       // 64 KB
  float* cbeta  = (float*)(ws + 45154304);                       // 2 KB
  float* pbeta  = (float*)(ws + 45156352);                       // 2 KB
  float* bb     = (float*)(ws + 45158400);                       // 4 KB

  prep_kernel<<<2816, 256, 0, stream>>>(x, mask, W_up, b_up, W_f, dp,
                                        Wf_bf, WupT, bb, hv, carry, lbeta, cbeta);
  mid2_kernel<<<272, 256, 0, stream>>>(Wf_bf, WupT, Wc, carry, cbeta, dp,
                                       Pbf, pbeta);
  pout_kernel<<<128, 256, 0, stream>>>(Pbf, Wc, pbeta, bb, Pout);
  gemm_main<<<1024, 256, 0, stream>>>(hv, Wc, Pout, lbeta, bb, b_f, dp, out);
}

// Round 4
// 226.917 us; speedup vs baseline: 1.0824x; 1.0824x over previous
//
#include <hip/hip_runtime.h>
#include <hip/hip_bf16.h>
#include <cstdint>
#include <cstddef>

// Sizes fixed by the reference problem.
#define DMODEL 1024
#define BATCH  4
#define SEQ    4096
#define BSROWS (BATCH*SEQ)     // 16384
#define CHUNK  32
#define NCHUNK (SEQ/CHUNK)     // 128
#define NCH_T  (BATCH*NCHUNK)  // 512 total chunks

typedef __attribute__((ext_vector_type(8))) short bf16x8;
typedef __attribute__((ext_vector_type(4))) float f32x4;

// ---- helpers ---------------------------------------------------------------

__device__ __forceinline__ unsigned short f2bf(float f) {
  union { float f; uint32_t u; } v; v.f = f;
  uint32_t u = v.u;
  u += 0x7FFFu + ((u >> 16) & 1u);   // round-to-nearest-even
  return (unsigned short)(u >> 16);
}

__device__ __forceinline__ float sigmoid_dev(const float* dp) {
  return 1.0f / (1.0f + expf(-dp[0]));
}

typedef __attribute__((address_space(1))) void void_g;
typedef __attribute__((address_space(3))) void void_l;

__device__ __forceinline__ void gl2lds16(const void* g, void* l) {
  __builtin_amdgcn_global_load_lds((void_g*)g, (void_l*)l, 16, 0, 0);
}

// ---- 64x64-tile NT K-loop (BK=64, XOR-8 swizzle) — used by mid2/pout -------
__device__ __forceinline__ void kloop64(
    const unsigned short* __restrict__ A, const unsigned short* __restrict__ B,
    int m0, int n0, f32x4 acc[2][2],
    unsigned short* As, unsigned short* Bs, int tid) {
  int lane = tid & 63, w = tid >> 6, wm = w & 1, wn = w >> 1;
  int quad = lane >> 4, l16 = lane & 15;
  int r = tid >> 3, cch = tid & 7;
  int g = cch ^ (r & 7);
  const bf16x8* Av = (const bf16x8*)As;
  const bf16x8* Bv = (const bf16x8*)Bs;
  for (int k0 = 0; k0 < DMODEL; k0 += 64) {
    gl2lds16(A + (size_t)(m0 + r) * DMODEL + k0 + g * 8,      As + r * 64 + cch * 8);
    gl2lds16(A + (size_t)(m0 + 32 + r) * DMODEL + k0 + g * 8, As + (32 + r) * 64 + cch * 8);
    gl2lds16(B + (size_t)(n0 + r) * DMODEL + k0 + g * 8,      Bs + r * 64 + cch * 8);
    gl2lds16(B + (size_t)(n0 + 32 + r) * DMODEL + k0 + g * 8, Bs + (32 + r) * 64 + cch * 8);
    __syncthreads();
    #pragma unroll
    for (int kk = 0; kk < 2; ++kk) {
      bf16x8 af[2], bfr[2];
      #pragma unroll
      for (int i = 0; i < 2; ++i) {
        int rowA = wm * 32 + i * 16 + l16;
        af[i]  = Av[rowA * 8 + ((kk * 4 + quad) ^ (l16 & 7))];
        int rowB = wn * 32 + i * 16 + l16;
        bfr[i] = Bv[rowB * 8 + ((kk * 4 + quad) ^ (l16 & 7))];
      }
      #pragma unroll
      for (int i = 0; i < 2; ++i)
        #pragma unroll
        for (int j = 0; j < 2; ++j)
          acc[i][j] = __builtin_amdgcn_mfma_f32_16x16x32_bf16(af[i], bfr[j], acc[i][j], 0, 0, 0);
    }
    __syncthreads();
  }
}

// ---- fused prep ------------------------------------------------------------
// blocks [0,512)    : single-pass local scan: hv = local scan (bf16) + carry
// blocks [512,1536) : W_f f32 -> bf16
// blocks [1536,2560): W_up f32 [c][d] -> bf16 transposed [d][c]
// blocks [2560,2816): bb[e] = dot(W_f[e,:], b_up)
// blocks [2816,2880): lbeta/cbeta (mask-only local scans, one thread per row)
__global__ __launch_bounds__(256) void prep_kernel(
    const float* __restrict__ x, const float* __restrict__ mask,
    const float* __restrict__ W_up, const float* __restrict__ b_up,
    const float* __restrict__ W_f, const float* __restrict__ dp,
    unsigned short* __restrict__ Wf_bf, unsigned short* __restrict__ WupT,
    float* __restrict__ bb, unsigned short* __restrict__ hv,
    float* __restrict__ carry, float* __restrict__ lbeta,
    float* __restrict__ cbeta) {
  __shared__ float tile[32][33];
  int blk = blockIdx.x;
  int tid = threadIdx.x;

  if (blk < 512) {
    float decay = sigmoid_dev(dp);
    int b = blk / NCHUNK, c = blk % NCHUNK;
    int base = b * SEQ + c * CHUNK;
    const float4* xp = (const float4*)(x + (size_t)base * DMODEL);
    const float* mp = mask + base;
    float4 h = make_float4(0.f, 0.f, 0.f, 0.f);
    #pragma unroll 8
    for (int s = 0; s < CHUNK; ++s) {
      float m = mp[s];
      float4 xv = xp[(size_t)s * (DMODEL / 4) + tid];
      h.x = decay * h.x + m * xv.x;
      h.y = decay * h.y + m * xv.y;
      h.z = decay * h.z + m * xv.z;
      h.w = decay * h.w + m * xv.w;
      ushort4 o;
      o.x = f2bf(h.x); o.y = f2bf(h.y); o.z = f2bf(h.z); o.w = f2bf(h.w);
      ((ushort4*)hv)[(size_t)(base + s) * (DMODEL / 4) + tid] = o;
    }
    ((float4*)carry)[(size_t)blk * (DMODEL / 4) + tid] = h;
  } else if (blk < 1536) {
    int i = (blk - 512) * 256 + tid;     // over D*D/4 float4s
    float4 v = ((const float4*)W_f)[i];
    ushort4 o;
    o.x = f2bf(v.x); o.y = f2bf(v.y); o.z = f2bf(v.z); o.w = f2bf(v.w);
    ((ushort4*)Wf_bf)[i] = o;
  } else if (blk < 2560) {
    int id = blk - 1536;
    int bx = id & 31, by = id >> 5;
    int tx = tid & 31, ty = tid >> 5;   // 32 x 8
    int xx = bx * 32 + tx;
    int y0 = by * 32;
    for (int j = ty; j < 32; j += 8)
      tile[j][tx] = W_up[(size_t)(y0 + j) * DMODEL + xx];
    __syncthreads();
    int ox = by * 32 + tx;
    int oy0 = bx * 32;
    for (int j = ty; j < 32; j += 8)
      WupT[(size_t)(oy0 + j) * DMODEL + ox] = f2bf(tile[tx][j]);
  } else if (blk < 2816) {
    int w = tid >> 6;
    int lane = tid & 63;
    int e = (blk - 2560) * 4 + w;
    float s = 0.f;
    for (int i = lane; i < DMODEL; i += 64)
      s += W_f[(size_t)e * DMODEL + i] * b_up[i];
    #pragma unroll
    for (int off = 32; off; off >>= 1) s += __shfl_down(s, off);
    if (lane == 0) bb[e] = s;
  } else {
    // beta local scans: one thread per (row); chain over its chunk prefix
    float decay = sigmoid_dev(dp);
    int t = (blk - 2816) * 256 + tid;     // 0..16383 global row
    int s = t & 31;
    int cbase = t & ~31;
    float hb = 0.f;
    for (int i = 0; i <= s; ++i)
      hb = decay * hb + mask[cbase + i];
    lbeta[t] = hb;
    if (s == 31) cbeta[t >> 5] = hb;
  }
}

// ---- mid2: gemm_wc (256 blocks, 64x64) + chunk-level scan (16 blocks) ------
__global__ __launch_bounds__(256) void mid2_kernel(
    const unsigned short* __restrict__ Wf_bf,
    const unsigned short* __restrict__ WupT,
    unsigned short* __restrict__ Wc,
    const float* __restrict__ carry, const float* __restrict__ cbeta,
    const float* __restrict__ dp,
    unsigned short* __restrict__ Pbf, float* __restrict__ pbeta) {
  __shared__ unsigned short As[64 * 64];
  __shared__ unsigned short Bs[64 * 64];
  int tid = threadIdx.x;
  if (blockIdx.x < 256) {
    // Wc[e][d] = sum_c Wf[e][c] * WupT[d][c]
    int mt = blockIdx.x >> 4, nt = blockIdx.x & 15;
    f32x4 acc[2][2] = {};
    kloop64(Wf_bf, WupT, mt * 64, nt * 64, acc, As, Bs, tid);
    int lane = tid & 63, w = tid >> 6, wm = w & 1, wn = w >> 1;
    int quad = lane >> 4, l16 = lane & 15;
    #pragma unroll
    for (int j = 0; j < 2; ++j) {
      int col = nt * 64 + wn * 32 + j * 16 + l16;
      #pragma unroll
      for (int i = 0; i < 2; ++i) {
        int rowb = mt * 64 + wm * 32 + i * 16 + quad * 4;
        #pragma unroll
        for (int rr = 0; rr < 4; ++rr)
          Wc[(size_t)(rowb + rr) * DMODEL + col] = f2bf(acc[i][j][rr]);
      }
    }
  } else {
    // exclusive chunk scan: Pbf[c] = state entering chunk c (bf16), pbeta f32
    float decay = sigmoid_dev(dp);
    float dL = powf(decay, (float)CHUNK);
    int gid = (blockIdx.x - 256) * 256 + tid;   // 0 .. 4095
    int b = gid >> 10, dd = gid & 1023;
    float P = 0.f;
    for (int c0 = 0; c0 < NCHUNK; c0 += 8) {
      float v[8];
      #pragma unroll
      for (int j = 0; j < 8; ++j)
        v[j] = carry[(size_t)(b * NCHUNK + c0 + j) * DMODEL + dd];
      #pragma unroll
      for (int j = 0; j < 8; ++j) {
        Pbf[(size_t)(b * NCHUNK + c0 + j) * DMODEL + dd] = f2bf(P);
        P = dL * P + v[j];
      }
    }
    if (dd == 0) {
      float Pb = 0.f;
      for (int c0 = 0; c0 < NCHUNK; c0 += 16) {
        float v[16];
        #pragma unroll
        for (int j = 0; j < 16; ++j) v[j] = cbeta[b * NCHUNK + c0 + j];
        #pragma unroll
        for (int j = 0; j < 16; ++j) {
          pbeta[b * NCHUNK + c0 + j] = Pb;
          Pb = dL * Pb + v[j];
        }
      }
    }
  }
}

// ---- pout: Pout[c][e] = sum_d Pbf[c][d]*Wc[e][d] + pbeta[c]*bb[e] ----------
__global__ __launch_bounds__(256) void pout_kernel(
    const unsigned short* __restrict__ Pbf,
    const unsigned short* __restrict__ Wc,
    const float* __restrict__ pbeta, const float* __restrict__ bb,
    float* __restrict__ Pout) {
  __shared__ unsigned short As[64 * 64];
  __shared__ unsigned short Bs[64 * 64];
  int tid = threadIdx.x;
  int mt = blockIdx.x >> 4, nt = blockIdx.x & 15;  // 8 x 16
  f32x4 acc[2][2] = {};
  kloop64(Pbf, Wc, mt * 64, nt * 64, acc, As, Bs, tid);
  int lane = tid & 63, w = tid >> 6, wm = w & 1, wn = w >> 1;
  int quad = lane >> 4, l16 = lane & 15;
  #pragma unroll
  for (int j = 0; j < 2; ++j) {
    int col = nt * 64 + wn * 32 + j * 16 + l16;
    float bbv = bb[col];
    #pragma unroll
    for (int i = 0; i < 2; ++i) {
      int rowb = mt * 64 + wm * 32 + i * 16 + quad * 4;
      #pragma unroll
      for (int rr = 0; rr < 4; ++rr) {
        int row = rowb + rr;
        Pout[(size_t)row * DMODEL + col] = acc[i][j][rr] + pbeta[row] * bbv;
      }
    }
  }
}

// ---- main GEMM: out = hv@Wc^T + decay^(s+1)*Pout[chunk] + lbeta*bb + b_f ---
// 128x128 tile, BK=32 (16 KB LDS), phi-swizzled LDS chunks for conflict-free
// ds_read_b128: phys chunk c of row r holds global chunk c ^ ((r>>1)&3).
// Staging keeps lane-linear LDS dest (tid*16B) by permuting the GLOBAL chunk.
__global__ __launch_bounds__(256, 4) void gemm_main(
    const unsigned short* __restrict__ A,    // hv (local scans) bf16 [16384][1024]
    const unsigned short* __restrict__ Bm,   // Wc bf16 [1024][1024] rows=e
    const float* __restrict__ Pout,          // [512][1024]
    const float* __restrict__ lbeta,
    const float* __restrict__ bb,
    const float* __restrict__ bias_f,
    const float* __restrict__ dp,
    float* __restrict__ out) {
  __shared__ unsigned short As[128 * 32];   // 8 KB
  __shared__ unsigned short Bs[128 * 32];   // 8 KB
  __shared__ float dpow[CHUNK];
  int tid = threadIdx.x;
  if (tid < CHUNK) {
    float decay = sigmoid_dev(dp);
    dpow[tid] = powf(decay, (float)(tid + 1));
  }
  int lane = tid & 63, w = tid >> 6, wm = w & 1, wn = w >> 1;
  int quad = lane >> 4, l16 = lane & 15;
  int r = tid >> 2;                 // 0..63
  int c4 = tid & 3;                 // phys chunk slot
  int g = c4 ^ ((r >> 1) & 3);      // global chunk to fetch
  int phi = (l16 >> 1) & 3;         // reader-side swizzle
  int m0 = (blockIdx.x & 127) * 128;   // consecutive blk -> same XCD shares A tiles
  int n0 = (blockIdx.x >> 7) * 128;
  f32x4 acc[4][4] = {};
  const bf16x8* Av = (const bf16x8*)As;
  const bf16x8* Bv = (const bf16x8*)Bs;
  for (int k0 = 0; k0 < DMODEL; k0 += 32) {
    gl2lds16(A + (size_t)(m0 + r) * DMODEL + k0 + g * 8,        As + r * 32 + c4 * 8);
    gl2lds16(A + (size_t)(m0 + 64 + r) * DMODEL + k0 + g * 8,   As + (64 + r) * 32 + c4 * 8);
    gl2lds16(Bm + (size_t)(n0 + r) * DMODEL + k0 + g * 8,       Bs + r * 32 + c4 * 8);
    gl2lds16(Bm + (size_t)(n0 + 64 + r) * DMODEL + k0 + g * 8,  Bs + (64 + r) * 32 + c4 * 8);
    __syncthreads();
    bf16x8 af[4], bfr[4];
    #pragma unroll
    for (int i = 0; i < 4; ++i) {
      int rowA = wm * 64 + i * 16 + l16;
      af[i]  = Av[rowA * 4 + (quad ^ phi)];
      int rowB = wn * 64 + i * 16 + l16;
      bfr[i] = Bv[rowB * 4 + (quad ^ phi)];
    }
    #pragma unroll
    for (int i = 0; i < 4; ++i)
      #pragma unroll
      for (int j = 0; j < 4; ++j)
        acc[i][j] = __builtin_amdgcn_mfma_f32_16x16x32_bf16(af[i], bfr[j], acc[i][j], 0, 0, 0);
    __syncthreads();
  }
  #pragma unroll
  for (int j = 0; j < 4; ++j) {
    int col = n0 + wn * 64 + j * 16 + l16;
    float bbv = bb[col];
    float bfv = bias_f[col];
    #pragma unroll
    for (int i = 0; i < 4; ++i) {
      int rowb = m0 + wm * 64 + i * 16 + quad * 4;
      #pragma unroll
      for (int rr = 0; rr < 4; ++rr) {
        int row = rowb + rr;
        float po = Pout[(size_t)(row >> 5) * DMODEL + col];
        out[(size_t)row * DMODEL + col] =
            acc[i][j][rr] + dpow[row & 31] * po + lbeta[row] * bbv + bfv;
      }
    }
  }
}

// ---- launch ----------------------------------------------------------------

extern "C" void kernel_launch(void* const* d_in, const int* in_sizes, int n_in,
                              void* d_out, int out_size, void* d_ws, size_t ws_size,
                              hipStream_t stream) {
  const float* x    = (const float*)d_in[0];
  const float* mask = (const float*)d_in[1];
  const float* W_up = (const float*)d_in[2];
  const float* b_up = (const float*)d_in[3];
  const float* W_f  = (const float*)d_in[4];
  const float* b_f  = (const float*)d_in[5];
  const float* dp   = (const float*)d_in[6];
  float* out = (float*)d_out;

  char* ws = (char*)d_ws;
  unsigned short* hv    = (unsigned short*)(ws);                 // 32 MB
  unsigned short* Wc    = (unsigned short*)(ws + 33554432);      // 2 MB
  unsigned short* Wf_bf = (unsigned short*)(ws + 35651584);      // 2 MB
  unsigned short* WupT  = (unsigned short*)(ws + 37748736);      // 2 MB
  float* carry  = (float*)(ws + 39845888);                       // 2 MB
  unsigned short* Pbf = (unsigned short*)(ws + 41943040);        // 1 MB
  float* Pout   = (float*)(ws + 42991616);                       // 2 MB
  float* lbeta  = (float*)(ws + 45088768);                       // 64 KB
  float* cbeta  = (float*)(ws + 45154304);                       // 2 KB
  float* pbeta  = (float*)(ws + 45156352);                       // 2 KB
  float* bb     = (float*)(ws + 45158400);                       // 4 KB

  prep_kernel<<<2880, 256, 0, stream>>>(x, mask, W_up, b_up, W_f, dp,
                                        Wf_bf, WupT, bb, hv, carry, lbeta, cbeta);
  mid2_kernel<<<272, 256, 0, stream>>>(Wf_bf, WupT, Wc, carry, cbeta, dp,
                                       Pbf, pbeta);
  pout_kernel<<<128, 256, 0, stream>>>(Pbf, Wc, pbeta, bb, Pout);
  gemm_main<<<1024, 256, 0, stream>>>(hv, Wc, Pout, lbeta, bb, b_f, dp, out);
}

// Round 5
// 203.483 us; speedup vs baseline: 1.2071x; 1.1152x over previous
//
#include <hip/hip_runtime.h>
#include <hip/hip_bf16.h>
#include <cstdint>
#include <cstddef>

// Sizes fixed by the reference problem.
#define DMODEL 1024
#define BATCH  4
#define SEQ    4096
#define BSROWS (BATCH*SEQ)     // 16384
#define CHUNK  32
#define NCHUNK (SEQ/CHUNK)     // 128
#define NCH_T  (BATCH*NCHUNK)  // 512 total chunks

typedef __attribute__((ext_vector_type(8))) short bf16x8;
typedef __attribute__((ext_vector_type(4))) float f32x4;

// ---- helpers ---------------------------------------------------------------

__device__ __forceinline__ unsigned short f2bf(float f) {
  union { float f; uint32_t u; } v; v.f = f;
  uint32_t u = v.u;
  u += 0x7FFFu + ((u >> 16) & 1u);   // round-to-nearest-even
  return (unsigned short)(u >> 16);
}

__device__ __forceinline__ float sigmoid_dev(const float* dp) {
  return 1.0f / (1.0f + expf(-dp[0]));
}

typedef __attribute__((address_space(1))) void void_g;
typedef __attribute__((address_space(3))) void void_l;

__device__ __forceinline__ void gl2lds16(const void* g, void* l) {
  __builtin_amdgcn_global_load_lds((void_g*)g, (void_l*)l, 16, 0, 0);
}

// ---- 64x64-tile NT K-loop (BK=64, XOR-8 swizzle) — used by mid2/pout -------
__device__ __forceinline__ void kloop64(
    const unsigned short* __restrict__ A, const unsigned short* __restrict__ B,
    int m0, int n0, f32x4 acc[2][2],
    unsigned short* As, unsigned short* Bs, int tid) {
  int lane = tid & 63, w = tid >> 6, wm = w & 1, wn = w >> 1;
  int quad = lane >> 4, l16 = lane & 15;
  int r = tid >> 3, cch = tid & 7;
  int g = cch ^ (r & 7);
  const bf16x8* Av = (const bf16x8*)As;
  const bf16x8* Bv = (const bf16x8*)Bs;
  for (int k0 = 0; k0 < DMODEL; k0 += 64) {
    gl2lds16(A + (size_t)(m0 + r) * DMODEL + k0 + g * 8,      As + r * 64 + cch * 8);
    gl2lds16(A + (size_t)(m0 + 32 + r) * DMODEL + k0 + g * 8, As + (32 + r) * 64 + cch * 8);
    gl2lds16(B + (size_t)(n0 + r) * DMODEL + k0 + g * 8,      Bs + r * 64 + cch * 8);
    gl2lds16(B + (size_t)(n0 + 32 + r) * DMODEL + k0 + g * 8, Bs + (32 + r) * 64 + cch * 8);
    __syncthreads();
    #pragma unroll
    for (int kk = 0; kk < 2; ++kk) {
      bf16x8 af[2], bfr[2];
      #pragma unroll
      for (int i = 0; i < 2; ++i) {
        int rowA = wm * 32 + i * 16 + l16;
        af[i]  = Av[rowA * 8 + ((kk * 4 + quad) ^ (l16 & 7))];
        int rowB = wn * 32 + i * 16 + l16;
        bfr[i] = Bv[rowB * 8 + ((kk * 4 + quad) ^ (l16 & 7))];
      }
      #pragma unroll
      for (int i = 0; i < 2; ++i)
        #pragma unroll
        for (int j = 0; j < 2; ++j)
          acc[i][j] = __builtin_amdgcn_mfma_f32_16x16x32_bf16(af[i], bfr[j], acc[i][j], 0, 0, 0);
    }
    __syncthreads();
  }
}

// ---- fused prep ------------------------------------------------------------
// blocks [0,512)    : single-pass local scan: hv = local scan (bf16) + carry
// blocks [512,1536) : W_f row e = blk-512 -> bf16, fused bb[e]=dot(W_f[e],b_up)
// blocks [1536,2560): W_up f32 [c][d] -> bf16 transposed [d][c]
// blocks [2560,2624): lbeta/cbeta (mask-only local scans, one thread per row)
__global__ __launch_bounds__(256) void prep_kernel(
    const float* __restrict__ x, const float* __restrict__ mask,
    const float* __restrict__ W_up, const float* __restrict__ b_up,
    const float* __restrict__ W_f, const float* __restrict__ dp,
    unsigned short* __restrict__ Wf_bf, unsigned short* __restrict__ WupT,
    float* __restrict__ bb, unsigned short* __restrict__ hv,
    float* __restrict__ carry, float* __restrict__ lbeta,
    float* __restrict__ cbeta) {
  __shared__ float tile[32][33];
  int blk = blockIdx.x;
  int tid = threadIdx.x;

  if (blk < 512) {
    float decay = sigmoid_dev(dp);
    int b = blk / NCHUNK, c = blk % NCHUNK;
    int base = b * SEQ + c * CHUNK;
    const float4* xp = (const float4*)(x + (size_t)base * DMODEL);
    // hoist mask row (32 floats = 8 float4) into registers
    const float4* mp4 = (const float4*)(mask + base);
    float mreg[32];
    #pragma unroll
    for (int q = 0; q < 8; ++q) {
      float4 t = mp4[q];
      mreg[q * 4 + 0] = t.x; mreg[q * 4 + 1] = t.y;
      mreg[q * 4 + 2] = t.z; mreg[q * 4 + 3] = t.w;
    }
    float4 h = make_float4(0.f, 0.f, 0.f, 0.f);
    #pragma unroll
    for (int s = 0; s < CHUNK; ++s) {
      float m = mreg[s];
      float4 xv = xp[(size_t)s * (DMODEL / 4) + tid];
      h.x = decay * h.x + m * xv.x;
      h.y = decay * h.y + m * xv.y;
      h.z = decay * h.z + m * xv.z;
      h.w = decay * h.w + m * xv.w;
      ushort4 o;
      o.x = f2bf(h.x); o.y = f2bf(h.y); o.z = f2bf(h.z); o.w = f2bf(h.w);
      ((ushort4*)hv)[(size_t)(base + s) * (DMODEL / 4) + tid] = o;
    }
    ((float4*)carry)[(size_t)blk * (DMODEL / 4) + tid] = h;
  } else if (blk < 1536) {
    // one W_f row per block: cast to bf16 + block-reduce dot with b_up
    int e = blk - 512;
    int lane = tid & 63, w = tid >> 6;
    float4 v = ((const float4*)(W_f + (size_t)e * DMODEL))[tid];
    float4 bu = ((const float4*)b_up)[tid];
    ushort4 o;
    o.x = f2bf(v.x); o.y = f2bf(v.y); o.z = f2bf(v.z); o.w = f2bf(v.w);
    ((ushort4*)(Wf_bf + (size_t)e * DMODEL))[tid] = o;
    float s = v.x * bu.x + v.y * bu.y + v.z * bu.z + v.w * bu.w;
    #pragma unroll
    for (int off = 32; off; off >>= 1) s += __shfl_down(s, off);
    if (lane == 0) ((float*)tile)[w] = s;
    __syncthreads();
    if (tid == 0)
      bb[e] = ((float*)tile)[0] + ((float*)tile)[1] +
              ((float*)tile)[2] + ((float*)tile)[3];
  } else if (blk < 2560) {
    int id = blk - 1536;
    int bx = id & 31, by = id >> 5;
    int tx = tid & 31, ty = tid >> 5;   // 32 x 8
    int xx = bx * 32 + tx;
    int y0 = by * 32;
    for (int j = ty; j < 32; j += 8)
      tile[j][tx] = W_up[(size_t)(y0 + j) * DMODEL + xx];
    __syncthreads();
    int ox = by * 32 + tx;
    int oy0 = bx * 32;
    for (int j = ty; j < 32; j += 8)
      WupT[(size_t)(oy0 + j) * DMODEL + ox] = f2bf(tile[tx][j]);
  } else {
    // beta local scans: one thread per row; chain over its chunk prefix
    float decay = sigmoid_dev(dp);
    int t = (blk - 2560) * 256 + tid;     // 0..16383 global row
    int s = t & 31;
    int cbase = t & ~31;
    float hb = 0.f;
    for (int i = 0; i <= s; ++i)
      hb = decay * hb + mask[cbase + i];
    lbeta[t] = hb;
    if (s == 31) cbeta[t >> 5] = hb;
  }
}

// ---- mid2: gemm_wc (256 blocks, 64x64) + chunk-level scan (16 blocks) ------
__global__ __launch_bounds__(256) void mid2_kernel(
    const unsigned short* __restrict__ Wf_bf,
    const unsigned short* __restrict__ WupT,
    unsigned short* __restrict__ Wc,
    const float* __restrict__ carry, const float* __restrict__ cbeta,
    const float* __restrict__ dp,
    unsigned short* __restrict__ Pbf, float* __restrict__ pbeta) {
  __shared__ unsigned short As[64 * 64];
  __shared__ unsigned short Bs[64 * 64];
  int tid = threadIdx.x;
  if (blockIdx.x < 256) {
    // Wc[e][d] = sum_c Wf[e][c] * WupT[d][c]
    int mt = blockIdx.x >> 4, nt = blockIdx.x & 15;
    f32x4 acc[2][2] = {};
    kloop64(Wf_bf, WupT, mt * 64, nt * 64, acc, As, Bs, tid);
    int lane = tid & 63, w = tid >> 6, wm = w & 1, wn = w >> 1;
    int quad = lane >> 4, l16 = lane & 15;
    #pragma unroll
    for (int j = 0; j < 2; ++j) {
      int col = nt * 64 + wn * 32 + j * 16 + l16;
      #pragma unroll
      for (int i = 0; i < 2; ++i) {
        int rowb = mt * 64 + wm * 32 + i * 16 + quad * 4;
        #pragma unroll
        for (int rr = 0; rr < 4; ++rr)
          Wc[(size_t)(rowb + rr) * DMODEL + col] = f2bf(acc[i][j][rr]);
      }
    }
  } else {
    // exclusive chunk scan: Pbf[c] = state entering chunk c (bf16), pbeta f32
    float decay = sigmoid_dev(dp);
    float dL = powf(decay, (float)CHUNK);
    int gid = (blockIdx.x - 256) * 256 + tid;   // 0 .. 4095
    int b = gid >> 10, dd = gid & 1023;
    float P = 0.f;
    for (int c0 = 0; c0 < NCHUNK; c0 += 8) {
      float v[8];
      #pragma unroll
      for (int j = 0; j < 8; ++j)
        v[j] = carry[(size_t)(b * NCHUNK + c0 + j) * DMODEL + dd];
      #pragma unroll
      for (int j = 0; j < 8; ++j) {
        Pbf[(size_t)(b * NCHUNK + c0 + j) * DMODEL + dd] = f2bf(P);
        P = dL * P + v[j];
      }
    }
    if (dd == 0) {
      float Pb = 0.f;
      for (int c0 = 0; c0 < NCHUNK; c0 += 16) {
        float v[16];
        #pragma unroll
        for (int j = 0; j < 16; ++j) v[j] = cbeta[b * NCHUNK + c0 + j];
        #pragma unroll
        for (int j = 0; j < 16; ++j) {
          pbeta[b * NCHUNK + c0 + j] = Pb;
          Pb = dL * Pb + v[j];
        }
      }
    }
  }
}

// ---- pout: Pout[c][e] = sum_d Pbf[c][d]*Wc[e][d] + pbeta[c]*bb[e] ----------
__global__ __launch_bounds__(256) void pout_kernel(
    const unsigned short* __restrict__ Pbf,
    const unsigned short* __restrict__ Wc,
    const float* __restrict__ pbeta, const float* __restrict__ bb,
    float* __restrict__ Pout) {
  __shared__ unsigned short As[64 * 64];
  __shared__ unsigned short Bs[64 * 64];
  int tid = threadIdx.x;
  int mt = blockIdx.x >> 4, nt = blockIdx.x & 15;  // 8 x 16
  f32x4 acc[2][2] = {};
  kloop64(Pbf, Wc, mt * 64, nt * 64, acc, As, Bs, tid);
  int lane = tid & 63, w = tid >> 6, wm = w & 1, wn = w >> 1;
  int quad = lane >> 4, l16 = lane & 15;
  #pragma unroll
  for (int j = 0; j < 2; ++j) {
    int col = nt * 64 + wn * 32 + j * 16 + l16;
    float bbv = bb[col];
    #pragma unroll
    for (int i = 0; i < 2; ++i) {
      int rowb = mt * 64 + wm * 32 + i * 16 + quad * 4;
      #pragma unroll
      for (int rr = 0; rr < 4; ++rr) {
        int row = rowb + rr;
        Pout[(size_t)row * DMODEL + col] = acc[i][j][rr] + pbeta[row] * bbv;
      }
    }
  }
}

// ---- main GEMM: out = hv@Wc^T + decay^(s+1)*Pout[chunk] + lbeta*bb + b_f ---
// 128x128 tile, BK=32 (16 KB LDS), phi-swizzled LDS chunks for conflict-free
// ds_read_b128. No min-waves bound: r4 showed pinning VGPR=64 starves the
// scheduler; VGPR ~116 / ~19% occ (r2 operating point) is faster.
__global__ __launch_bounds__(256) void gemm_main(
    const unsigned short* __restrict__ A,    // hv (local scans) bf16 [16384][1024]
    const unsigned short* __restrict__ Bm,   // Wc bf16 [1024][1024] rows=e
    const float* __restrict__ Pout,          // [512][1024]
    const float* __restrict__ lbeta,
    const float* __restrict__ bb,
    const float* __restrict__ bias_f,
    const float* __restrict__ dp,
    float* __restrict__ out) {
  __shared__ unsigned short As[128 * 32];   // 8 KB
  __shared__ unsigned short Bs[128 * 32];   // 8 KB
  __shared__ float dpow[CHUNK];
  int tid = threadIdx.x;
  if (tid < CHUNK) {
    float decay = sigmoid_dev(dp);
    dpow[tid] = powf(decay, (float)(tid + 1));
  }
  int lane = tid & 63, w = tid >> 6, wm = w & 1, wn = w >> 1;
  int quad = lane >> 4, l16 = lane & 15;
  int r = tid >> 2;                 // 0..63
  int c4 = tid & 3;                 // phys chunk slot
  int g = c4 ^ ((r >> 1) & 3);      // global chunk to fetch
  int phi = (l16 >> 1) & 3;         // reader-side swizzle
  int m0 = (blockIdx.x & 127) * 128;   // m-major: same-m blocks share an XCD
  int n0 = (blockIdx.x >> 7) * 128;
  f32x4 acc[4][4] = {};
  const bf16x8* Av = (const bf16x8*)As;
  const bf16x8* Bv = (const bf16x8*)Bs;
  for (int k0 = 0; k0 < DMODEL; k0 += 32) {
    gl2lds16(A + (size_t)(m0 + r) * DMODEL + k0 + g * 8,        As + r * 32 + c4 * 8);
    gl2lds16(A + (size_t)(m0 + 64 + r) * DMODEL + k0 + g * 8,   As + (64 + r) * 32 + c4 * 8);
    gl2lds16(Bm + (size_t)(n0 + r) * DMODEL + k0 + g * 8,       Bs + r * 32 + c4 * 8);
    gl2lds16(Bm + (size_t)(n0 + 64 + r) * DMODEL + k0 + g * 8,  Bs + (64 + r) * 32 + c4 * 8);
    __syncthreads();
    bf16x8 af[4], bfr[4];
    #pragma unroll
    for (int i = 0; i < 4; ++i) {
      int rowA = wm * 64 + i * 16 + l16;
      af[i]  = Av[rowA * 4 + (quad ^ phi)];
      int rowB = wn * 64 + i * 16 + l16;
      bfr[i] = Bv[rowB * 4 + (quad ^ phi)];
    }
    #pragma unroll
    for (int i = 0; i < 4; ++i)
      #pragma unroll
      for (int j = 0; j < 4; ++j)
        acc[i][j] = __builtin_amdgcn_mfma_f32_16x16x32_bf16(af[i], bfr[j], acc[i][j], 0, 0, 0);
    __syncthreads();
  }
  #pragma unroll
  for (int j = 0; j < 4; ++j) {
    int col = n0 + wn * 64 + j * 16 + l16;
    float bbv = bb[col];
    float bfv = bias_f[col];
    #pragma unroll
    for (int i = 0; i < 4; ++i) {
      int rowb = m0 + wm * 64 + i * 16 + quad * 4;
      #pragma unroll
      for (int rr = 0; rr < 4; ++rr) {
        int row = rowb + rr;
        float po = Pout[(size_t)(row >> 5) * DMODEL + col];
        out[(size_t)row * DMODEL + col] =
            acc[i][j][rr] + dpow[row & 31] * po + lbeta[row] * bbv + bfv;
      }
    }
  }
}

// ---- launch ----------------------------------------------------------------

extern "C" void kernel_launch(void* const* d_in, const int* in_sizes, int n_in,
                              void* d_out, int out_size, void* d_ws, size_t ws_size,
                              hipStream_t stream) {
  const float* x    = (const float*)d_in[0];
  const float* mask = (const float*)d_in[1];
  const float* W_up = (const float*)d_in[2];
  const float* b_up = (const float*)d_in[3];
  const float* W_f  = (const float*)d_in[4];
  const float* b_f  = (const float*)d_in[5];
  const float* dp   = (const float*)d_in[6];
  float* out = (float*)d_out;

  char* ws = (char*)d_ws;
  unsigned short* hv    = (unsigned short*)(ws);                 // 32 MB
  unsigned short* Wc    = (unsigned short*)(ws + 33554432);      // 2 MB
  unsigned short* Wf_bf = (unsigned short*)(ws + 35651584);      // 2 MB
  unsigned short* WupT  = (unsigned short*)(ws + 37748736);      // 2 MB
  float* carry  = (float*)(ws + 39845888);                       // 2 MB
  unsigned short* Pbf = (unsigned short*)(ws + 41943040);        // 1 MB
  float* Pout   = (float*)(ws + 42991616);                       // 2 MB
  float* lbeta  = (float*)(ws + 45088768);                       // 64 KB
  float* cbeta  = (float*)(ws + 45154304);                       // 2 KB
  float* pbeta  = (float*)(ws + 45156352);                       // 2 KB
  float* bb     = (float*)(ws + 45158400);                       // 4 KB

  prep_kernel<<<2624, 256, 0, stream>>>(x, mask, W_up, b_up, W_f, dp,
                                        Wf_bf, WupT, bb, hv, carry, lbeta, cbeta);
  mid2_kernel<<<272, 256, 0, stream>>>(Wf_bf, WupT, Wc, carry, cbeta, dp,
                                       Pbf, pbeta);
  pout_kernel<<<128, 256, 0, stream>>>(Pbf, Wc, pbeta, bb, Pout);
  gemm_main<<<1024, 256, 0, stream>>>(hv, Wc, Pout, lbeta, bb, b_f, dp, out);
}